// Round 1
// baseline (131.510 us; speedup 1.0000x reference)
//
#include <hip/hip_runtime.h>

#define T_DIM 4096
#define D_DIM 128

// One thread per float4 (4 consecutive d of the same (b,t)).
// valid := x != 0. For invalid positions, scan backward/forward along t
// (stride D_DIM) to find prev/next valid, then apply the reference's
// linspace-fill semantics exactly.
__global__ void __launch_bounds__(256) imputer_kernel(
    const float* __restrict__ x, float* __restrict__ out, int total4) {
    int i4 = blockIdx.x * blockDim.x + threadIdx.x;
    if (i4 >= total4) return;

    float4 v = reinterpret_cast<const float4*>(x)[i4];

    // Fast path: all 4 observed -> passthrough (≈52% of threads).
    if (v.x != 0.f && v.y != 0.f && v.z != 0.f && v.w != 0.f) {
        reinterpret_cast<float4*>(out)[i4] = v;
        return;
    }

    int flat = i4 * 4;               // element index of component 0
    int row  = flat / D_DIM;         // = b*T + t
    int d0   = flat - row * D_DIM;   // d of component 0
    int t    = row & (T_DIM - 1);    // T_DIM is power of 2
    int base = (row - t) * D_DIM;    // offset of x[b][0][0]

    float vv[4] = {v.x, v.y, v.z, v.w};
    float res[4];

#pragma unroll
    for (int c = 0; c < 4; ++c) {
        float xv = vv[c];
        if (xv != 0.f) { res[c] = xv; continue; }
        int d = d0 + c;

        // prev valid (or -1)
        int s = t - 1;
        while (s >= 0 && x[base + s * D_DIM + d] == 0.f) --s;
        // next valid (or T)
        int e = t + 1;
        while (e < T_DIM && x[base + e * D_DIM + d] == 0.f) ++e;

        int start = s < 0 ? 0 : s;
        int end   = (e < T_DIM) ? e : (T_DIM - 1);

        if (start >= end || t >= end) { res[c] = xv; continue; }  // keep (== 0)

        float a  = x[base + start * D_DIM + d];
        float bv = x[base + end   * D_DIM + d];
        int denom = end - start - 1;
        res[c] = (denom > 0)
                   ? a + (float)(t - start) * (bv - a) / (float)denom
                   : a;
    }

    float4 o;
    o.x = res[0]; o.y = res[1]; o.z = res[2]; o.w = res[3];
    reinterpret_cast<float4*>(out)[i4] = o;
}

extern "C" void kernel_launch(void* const* d_in, const int* in_sizes, int n_in,
                              void* d_out, int out_size, void* d_ws, size_t ws_size,
                              hipStream_t stream) {
    const float* x = (const float*)d_in[0];
    float* out = (float*)d_out;
    int total4 = in_sizes[0] / 4;   // 64*4096*128 / 4 = 8,388,608
    int threads = 256;
    int blocks = (total4 + threads - 1) / threads;
    imputer_kernel<<<blocks, threads, 0, stream>>>(x, out, total4);
}

// Round 2
// 77.849 us; speedup vs baseline: 1.6893x; 1.6893x over previous
//
#include <hip/hip_runtime.h>

#define T_DIM 4096
#define D_DIM 128
#define Q_PER_ROW (D_DIM / 4)   // 32 float4 per (b,t) row

// One thread per float4 (4 consecutive d of one (b,t)).
// Slow path: batched speculative scans — load 4 whole float4 rows per round
// (independent loads, one latency round-trip), resolve all 4 components
// against each row. The scan rows themselves supply the a/b endpoint values.
__global__ void __launch_bounds__(256) imputer_kernel(
    const float* __restrict__ x, float* __restrict__ out, int total4) {
    int i4 = blockIdx.x * blockDim.x + threadIdx.x;
    if (i4 >= total4) return;

    const float4* __restrict__ x4 = reinterpret_cast<const float4*>(x);
    float4 v = x4[i4];

    if (v.x != 0.f && v.y != 0.f && v.z != 0.f && v.w != 0.f) {
        reinterpret_cast<float4*>(out)[i4] = v;
        return;
    }

    int q    = i4 & (Q_PER_ROW - 1);
    int row  = i4 >> 5;              // b*T + t
    int t    = row & (T_DIM - 1);
    int col0 = (row - t) * Q_PER_ROW + q;   // float4 index at t=0, same (b,q)

    float vv[4] = {v.x, v.y, v.z, v.w};
    float a_[4] = {0.f, 0.f, 0.f, 0.f};
    float b_[4] = {0.f, 0.f, 0.f, 0.f};
    int   s_[4] = {-1, -1, -1, -1};
    int   e_[4] = {T_DIM, T_DIM, T_DIM, T_DIM};

    unsigned need0 = 0;
#pragma unroll
    for (int c = 0; c < 4; ++c)
        if (vv[c] == 0.f) need0 |= 1u << c;

    // ---- backward scan: find prev valid (s_, a_) per component ----
    {
        unsigned need = need0;
        int k = 1;
        while (need && t - k >= 0) {
            int n = t - k + 1;            // rows remaining below
            float4 r0, r1, r2, r3;
            r0 = x4[col0 + (t - k) * Q_PER_ROW];
            if (n > 1) r1 = x4[col0 + (t - k - 1) * Q_PER_ROW];
            if (n > 2) r2 = x4[col0 + (t - k - 2) * Q_PER_ROW];
            if (n > 3) r3 = x4[col0 + (t - k - 3) * Q_PER_ROW];

#define PROC_B(R, OFF)                                                        \
            {                                                                 \
                float rr0 = R.x, rr1 = R.y, rr2 = R.z, rr3 = R.w;             \
                if ((need & 1u) && rr0 != 0.f) { s_[0] = t - k - (OFF); a_[0] = rr0; need &= ~1u; } \
                if ((need & 2u) && rr1 != 0.f) { s_[1] = t - k - (OFF); a_[1] = rr1; need &= ~2u; } \
                if ((need & 4u) && rr2 != 0.f) { s_[2] = t - k - (OFF); a_[2] = rr2; need &= ~4u; } \
                if ((need & 8u) && rr3 != 0.f) { s_[3] = t - k - (OFF); a_[3] = rr3; need &= ~8u; } \
            }
            PROC_B(r0, 0)
            if (n > 1) PROC_B(r1, 1)
            if (n > 2) PROC_B(r2, 2)
            if (n > 3) PROC_B(r3, 3)
#undef PROC_B
            k += 4;
        }
    }

    // ---- forward scan: find next valid (e_, b_) per component ----
    {
        unsigned need = need0;
        int k = 1;
        while (need && t + k < T_DIM) {
            int n = T_DIM - (t + k);      // rows remaining above
            float4 r0, r1, r2, r3;
            r0 = x4[col0 + (t + k) * Q_PER_ROW];
            if (n > 1) r1 = x4[col0 + (t + k + 1) * Q_PER_ROW];
            if (n > 2) r2 = x4[col0 + (t + k + 2) * Q_PER_ROW];
            if (n > 3) r3 = x4[col0 + (t + k + 3) * Q_PER_ROW];

#define PROC_F(R, OFF)                                                        \
            {                                                                 \
                float rr0 = R.x, rr1 = R.y, rr2 = R.z, rr3 = R.w;             \
                if ((need & 1u) && rr0 != 0.f) { e_[0] = t + k + (OFF); b_[0] = rr0; need &= ~1u; } \
                if ((need & 2u) && rr1 != 0.f) { e_[1] = t + k + (OFF); b_[1] = rr1; need &= ~2u; } \
                if ((need & 4u) && rr2 != 0.f) { e_[2] = t + k + (OFF); b_[2] = rr2; need &= ~4u; } \
                if ((need & 8u) && rr3 != 0.f) { e_[3] = t + k + (OFF); b_[3] = rr3; need &= ~8u; } \
            }
            PROC_F(r0, 0)
            if (n > 1) PROC_F(r1, 1)
            if (n > 2) PROC_F(r2, 2)
            if (n > 3) PROC_F(r3, 3)
#undef PROC_F
            k += 4;
        }
    }

    // ---- apply reference fill semantics ----
    float res[4];
#pragma unroll
    for (int c = 0; c < 4; ++c) {
        if (vv[c] != 0.f) { res[c] = vv[c]; continue; }
        int start = s_[c] < 0 ? 0 : s_[c];
        int end   = e_[c] < T_DIM ? e_[c] : T_DIM - 1;
        if (start >= end || t >= end) { res[c] = 0.f; continue; }
        int denom = end - start - 1;
        res[c] = (denom > 0)
                   ? a_[c] + (float)(t - start) * (b_[c] - a_[c]) / (float)denom
                   : a_[c];
    }

    float4 o;
    o.x = res[0]; o.y = res[1]; o.z = res[2]; o.w = res[3];
    reinterpret_cast<float4*>(out)[i4] = o;
}

extern "C" void kernel_launch(void* const* d_in, const int* in_sizes, int n_in,
                              void* d_out, int out_size, void* d_ws, size_t ws_size,
                              hipStream_t stream) {
    const float* x = (const float*)d_in[0];
    float* out = (float*)d_out;
    int total4 = in_sizes[0] / 4;
    int threads = 256;
    int blocks = (total4 + threads - 1) / threads;
    imputer_kernel<<<blocks, threads, 0, stream>>>(x, out, total4);
}